// Round 1
// baseline (749.342 us; speedup 1.0000x reference)
//
#include <hip/hip_runtime.h>
#include <stdint.h>

#define Hh 8
#define Bb 32
#define Tt 512
#define Ee 512
#define Nn 16384            // Bb*Tt
#define GAMMA_ 1.5f
#define BN_EPS_ 1e-5f

typedef _Float16 f16x4 __attribute__((ext_vector_type(4)));
typedef _Float16 f16x8 __attribute__((ext_vector_type(8)));
typedef float    f32x4 __attribute__((ext_vector_type(4)));

__device__ __forceinline__ void async_ld16(void* lds, const void* g) {
    __builtin_amdgcn_global_load_lds(
        (const __attribute__((address_space(1))) void*)g,
        (__attribute__((address_space(3))) void*)lds, 16, 0, 0);
}

// ---------------- K0: fp32 -> f16 convert (x then W, contiguous) ----------------
__global__ __launch_bounds__(256) void cvt_kernel(const float* __restrict__ x,
                                                  const float* __restrict__ W,
                                                  _Float16* __restrict__ xh,
                                                  _Float16* __restrict__ wh) {
    const int NX = Bb * Tt * Ee;               // 8388608, divisible by 4
    int i = (blockIdx.x * 256 + threadIdx.x) * 4;
    if (i < NX) {
        float4 v = *(const float4*)(x + i);
        f16x4 o = {(_Float16)v.x, (_Float16)v.y, (_Float16)v.z, (_Float16)v.w};
        *(f16x4*)(xh + i) = o;
    } else {
        int j = i - NX;                        // 0 .. 2097151
        float4 v = *(const float4*)(W + j);
        f16x4 o = {(_Float16)v.x, (_Float16)v.y, (_Float16)v.z, (_Float16)v.w};
        *(f16x4*)(wh + j) = o;
    }
}

// ---------------- K1: batched NT GEMM, f16 MFMA, BN-stat atomics in epilogue ----
// grid (Nn/128=128, Ee/128=4, Hh=8), 256 threads (4 waves, 2x2 of 64x64)
__global__ __launch_bounds__(256) void gemm_kernel(const _Float16* __restrict__ A,
                                                   const _Float16* __restrict__ Bm,
                                                   _Float16* __restrict__ C,
                                                   float* __restrict__ sums,
                                                   float* __restrict__ sumsq) {
    __shared__ alignas(16) _Float16 As[128 * 32];   // 8 KB
    __shared__ alignas(16) _Float16 Bs[128 * 32];   // 8 KB
    const int h  = blockIdx.z;
    const int mb = blockIdx.x * 128;
    const int nb = blockIdx.y * 128;
    const int t    = threadIdx.x;
    const int lane = t & 63;
    const int w    = t >> 6;
    const int wm   = (w >> 1) * 64;
    const int wn   = (w & 1) * 64;
    const int quad = lane >> 4;
    const int l16  = lane & 15;

    // staging: thread t loads 16B chunks c=t and c=t+256; row=c>>2, k-off=(c&3)*8
    const _Float16* Ap = A + (size_t)(mb + (t >> 2)) * Ee + (t & 3) * 8;
    const _Float16* Bp = Bm + (size_t)h * Ee * Ee + (size_t)(nb + (t >> 2)) * Ee + (t & 3) * 8;

    f32x4 acc[4][4] = {};

    for (int k0 = 0; k0 < Ee; k0 += 32) {
        async_ld16(&As[t * 8],        Ap + k0);
        async_ld16(&As[2048 + t * 8], Ap + 64 * Ee + k0);
        async_ld16(&Bs[t * 8],        Bp + k0);
        async_ld16(&Bs[2048 + t * 8], Bp + 64 * Ee + k0);
        __syncthreads();
        f16x8 a8[4], b8[4];
#pragma unroll
        for (int mt = 0; mt < 4; ++mt)
            a8[mt] = *(const f16x8*)(&As[(wm + mt * 16 + l16) * 32 + quad * 8]);
#pragma unroll
        for (int nt = 0; nt < 4; ++nt)
            b8[nt] = *(const f16x8*)(&Bs[(wn + nt * 16 + l16) * 32 + quad * 8]);
#pragma unroll
        for (int mt = 0; mt < 4; ++mt)
#pragma unroll
            for (int nt = 0; nt < 4; ++nt)
                acc[mt][nt] = __builtin_amdgcn_mfma_f32_16x16x32_f16(a8[mt], b8[nt], acc[mt][nt], 0, 0, 0);
        __syncthreads();
    }

    // BN partial sums: reduce over rows (mt,r) then across quads (lanes xor 16,32)
#pragma unroll
    for (int nt = 0; nt < 4; ++nt) {
        float s = 0.f, ss = 0.f;
#pragma unroll
        for (int mt = 0; mt < 4; ++mt)
#pragma unroll
            for (int r = 0; r < 4; ++r) { float v = acc[mt][nt][r]; s += v; ss += v * v; }
        s  += __shfl_xor(s, 16, 64);  s  += __shfl_xor(s, 32, 64);
        ss += __shfl_xor(ss, 16, 64); ss += __shfl_xor(ss, 32, 64);
        if (quad == 0) {
            int col = nb + wn + nt * 16 + l16;
            atomicAdd(&sums[h * Ee + col], s);
            atomicAdd(&sumsq[h * Ee + col], ss);
        }
    }

    // store C (f16): C/D layout col=lane&15, row=quad*4+reg
    _Float16* Cp = C + (size_t)h * Nn * Ee;
#pragma unroll
    for (int mt = 0; mt < 4; ++mt)
#pragma unroll
        for (int r = 0; r < 4; ++r) {
            int row = mb + wm + mt * 16 + quad * 4 + r;
            size_t off = (size_t)row * Ee + nb + wn + l16;
#pragma unroll
            for (int nt = 0; nt < 4; ++nt)
                Cp[off + nt * 16] = (_Float16)acc[mt][nt][r];
        }
}

// ---------------- K2: finalize BN stats into affine coefs -----------------------
__global__ __launch_bounds__(256) void stats_kernel(const float* __restrict__ sums,
                                                    const float* __restrict__ sumsq,
                                                    const float* __restrict__ bnw,
                                                    const float* __restrict__ bnb,
                                                    float* __restrict__ cA,
                                                    float* __restrict__ cB) {
    int i = blockIdx.x * 256 + threadIdx.x;    // 0..4095
    float mean = sums[i] * (1.0f / Nn);
    float var  = sumsq[i] * (1.0f / Nn) - mean * mean;
    float inv  = rsqrtf(var + BN_EPS_);
    float a    = bnw[i] * inv;
    cA[i] = a;
    cB[i] = bnb[i] - mean * a;
}

// ---------------- K3: per-row head scan: sparsemax (Michelot, exact) ------------
// 256 threads = 4 waves, each wave owns one row n. Lane holds elems
// [lane*4, lane*4+4) and [256+lane*4, 256+lane*4+4)  (coalesced float4 chunks).
__global__ __launch_bounds__(256) void rows_kernel(const float* __restrict__ x,
                                                   const _Float16* __restrict__ lg,
                                                   const float* __restrict__ cA,
                                                   const float* __restrict__ cB,
                                                   float* __restrict__ out) {
    const int n    = blockIdx.x * 4 + (threadIdx.x >> 6);
    const int lane = threadIdx.x & 63;
    const int e0   = lane * 4;                 // first chunk; second at +256
    const int bb   = n >> 9;                   // n / Tt
    const int tt   = n & 511;                  // n % Tt

    float xr[8], prior[8], z[8], mk[8];
    {
        const float* xp = x + (size_t)n * Ee;
        float4 x0 = *(const float4*)(xp + e0);
        float4 x1 = *(const float4*)(xp + 256 + e0);
        xr[0]=x0.x; xr[1]=x0.y; xr[2]=x0.z; xr[3]=x0.w;
        xr[4]=x1.x; xr[5]=x1.y; xr[6]=x1.z; xr[7]=x1.w;
    }
#pragma unroll
    for (int j = 0; j < 8; ++j) prior[j] = 1.0f;

    float* omx = out;                               // (H,B,T,E) flat = (H,N,E)
    float* omk = out + (size_t)Hh * Nn * Ee;        // (B,H,T,E)

    for (int h = 0; h < Hh; ++h) {
        const _Float16* lp = lg + (size_t)h * Nn * Ee + (size_t)n * Ee;
        f16x4 l0 = *(const f16x4*)(lp + e0);
        f16x4 l1 = *(const f16x4*)(lp + 256 + e0);
        const float* ap = cA + h * Ee;
        const float* bp = cB + h * Ee;
        float4 a0 = *(const float4*)(ap + e0);
        float4 a1 = *(const float4*)(ap + 256 + e0);
        float4 b0 = *(const float4*)(bp + e0);
        float4 b1 = *(const float4*)(bp + 256 + e0);
        float av[8] = {a0.x,a0.y,a0.z,a0.w,a1.x,a1.y,a1.z,a1.w};
        float bv[8] = {b0.x,b0.y,b0.z,b0.w,b1.x,b1.y,b1.z,b1.w};
        float lv[8] = {(float)l0[0],(float)l0[1],(float)l0[2],(float)l0[3],
                       (float)l1[0],(float)l1[1],(float)l1[2],(float)l1[3]};
#pragma unroll
        for (int j = 0; j < 8; ++j)
            z[j] = (lv[j] * av[j] + bv[j]) * prior[j];

        // Michelot: exact sparsemax threshold. Sets are nested, counts exact.
        float tau = -1e30f;
        int cprev = -1;
        for (int it = 0; it < 600; ++it) {
            float s2 = 0.f, cf = 0.f;
#pragma unroll
            for (int j = 0; j < 8; ++j)
                if (z[j] > tau) { s2 += z[j]; cf += 1.0f; }
#pragma unroll
            for (int m = 32; m >= 1; m >>= 1) {
                s2 += __shfl_xor(s2, m, 64);
                cf += __shfl_xor(cf, m, 64);
            }
            int c = (int)cf;
            if (c == cprev) break;
            cprev = c;
            tau = (s2 - 1.0f) / cf;
        }

#pragma unroll
        for (int j = 0; j < 8; ++j) {
            mk[j] = fmaxf(z[j] - tau, 0.0f);
            prior[j] *= fmaxf(GAMMA_ - mk[j], 0.0f);
        }

        size_t oxoff = ((size_t)h * Nn + n) * Ee;
        size_t okoff = (((size_t)bb * Hh + h) * Tt + tt) * Ee;
        float4 vx0 = {xr[0]*mk[0], xr[1]*mk[1], xr[2]*mk[2], xr[3]*mk[3]};
        float4 vx1 = {xr[4]*mk[4], xr[5]*mk[5], xr[6]*mk[6], xr[7]*mk[7]};
        float4 vm0 = {mk[0], mk[1], mk[2], mk[3]};
        float4 vm1 = {mk[4], mk[5], mk[6], mk[7]};
        *(float4*)(omx + oxoff + e0)       = vx0;
        *(float4*)(omx + oxoff + 256 + e0) = vx1;
        *(float4*)(omk + okoff + e0)       = vm0;
        *(float4*)(omk + okoff + 256 + e0) = vm1;
    }
}

extern "C" void kernel_launch(void* const* d_in, const int* in_sizes, int n_in,
                              void* d_out, int out_size, void* d_ws, size_t ws_size,
                              hipStream_t stream) {
    const float* x   = (const float*)d_in[0];
    const float* W   = (const float*)d_in[1];
    const float* bnw = (const float*)d_in[2];
    const float* bnb = (const float*)d_in[3];
    float* out = (float*)d_out;

    uint8_t* ws = (uint8_t*)d_ws;
    _Float16* xh = (_Float16*)(ws);                    // 16,777,216 B
    _Float16* wh = (_Float16*)(ws + 16777216);         //  4,194,304 B
    _Float16* lg = (_Float16*)(ws + 20971520);         // 134,217,728 B
    float* sums  = (float*)(ws + 155189248);           // 16,384 B
    float* sumsq = (float*)(ws + 155205632);           // 16,384 B
    float* cA    = (float*)(ws + 155222016);           // 16,384 B
    float* cB    = (float*)(ws + 155238400);           // 16,384 B (total ~148 MB)

    hipMemsetAsync(sums, 0, 2 * 4096 * sizeof(float), stream);  // sums+sumsq contiguous

    cvt_kernel<<<10240, 256, 0, stream>>>(x, W, xh, wh);
    gemm_kernel<<<dim3(128, 4, 8), 256, 0, stream>>>(xh, wh, lg, sums, sumsq);
    stats_kernel<<<16, 256, 0, stream>>>(sums, sumsq, bnw, bnb, cA, cB);
    rows_kernel<<<4096, 256, 0, stream>>>(x, lg, cA, cB, out);
}

// Round 2
// 675.986 us; speedup vs baseline: 1.1085x; 1.1085x over previous
//
#include <hip/hip_runtime.h>
#include <stdint.h>

#define Hh 8
#define Bb 32
#define Tt 512
#define Ee 512
#define Nn 16384            // Bb*Tt
#define GAMMA_ 1.5f
#define BN_EPS_ 1e-5f

typedef _Float16 f16x4 __attribute__((ext_vector_type(4)));
typedef _Float16 f16x8 __attribute__((ext_vector_type(8)));
typedef float    f32x4 __attribute__((ext_vector_type(4)));

__device__ __forceinline__ void async_ld16(void* lds, const void* g) {
    __builtin_amdgcn_global_load_lds(
        (const __attribute__((address_space(1))) void*)g,
        (__attribute__((address_space(3))) void*)lds, 16, 0, 0);
}

// Full-wave (64-lane) f32 sum via DPP (pure VALU, no DS pipe).
// row_shr:1/2/4/8 then row_bcast:15/31; result valid in lane 63 -> readlane.
__device__ __forceinline__ float dpp_sum64(float v) {
    int t;
    t = __builtin_amdgcn_update_dpp(0, __float_as_int(v), 0x111, 0xf, 0xf, true);
    v += __int_as_float(t);
    t = __builtin_amdgcn_update_dpp(0, __float_as_int(v), 0x112, 0xf, 0xf, true);
    v += __int_as_float(t);
    t = __builtin_amdgcn_update_dpp(0, __float_as_int(v), 0x114, 0xf, 0xf, true);
    v += __int_as_float(t);
    t = __builtin_amdgcn_update_dpp(0, __float_as_int(v), 0x118, 0xf, 0xf, true);
    v += __int_as_float(t);
    t = __builtin_amdgcn_update_dpp(0, __float_as_int(v), 0x142, 0xf, 0xf, true);
    v += __int_as_float(t);
    t = __builtin_amdgcn_update_dpp(0, __float_as_int(v), 0x143, 0xf, 0xf, true);
    v += __int_as_float(t);
    return __int_as_float(__builtin_amdgcn_readlane(__float_as_int(v), 63));
}

// ---------------- K0: fp32 -> f16 convert (x then W, contiguous) ----------------
__global__ __launch_bounds__(256) void cvt_kernel(const float* __restrict__ x,
                                                  const float* __restrict__ W,
                                                  _Float16* __restrict__ xh,
                                                  _Float16* __restrict__ wh) {
    const int NX = Bb * Tt * Ee;               // 8388608, divisible by 4
    int i = (blockIdx.x * 256 + threadIdx.x) * 4;
    if (i < NX) {
        float4 v = *(const float4*)(x + i);
        f16x4 o = {(_Float16)v.x, (_Float16)v.y, (_Float16)v.z, (_Float16)v.w};
        *(f16x4*)(xh + i) = o;
    } else {
        int j = i - NX;                        // 0 .. 2097151
        float4 v = *(const float4*)(W + j);
        f16x4 o = {(_Float16)v.x, (_Float16)v.y, (_Float16)v.z, (_Float16)v.w};
        *(f16x4*)(wh + j) = o;
    }
}

// ---------------- K1: batched NT GEMM, f16 MFMA, double-buffered LDS ------------
// grid (Nn/128=128, Ee/128=4, Hh=8), 256 threads (4 waves, 2x2 of 64x64)
__global__ __launch_bounds__(256) void gemm_kernel(const _Float16* __restrict__ A,
                                                   const _Float16* __restrict__ Bm,
                                                   _Float16* __restrict__ C,
                                                   float* __restrict__ sums,
                                                   float* __restrict__ sumsq) {
    __shared__ alignas(16) _Float16 As[2][128 * 32];   // 2 x 8 KB
    __shared__ alignas(16) _Float16 Bs[2][128 * 32];   // 2 x 8 KB
    const int h  = blockIdx.z;
    const int mb = blockIdx.x * 128;
    const int nb = blockIdx.y * 128;
    const int t    = threadIdx.x;
    const int lane = t & 63;
    const int w    = t >> 6;
    const int wm   = (w >> 1) * 64;
    const int wn   = (w & 1) * 64;
    const int quad = lane >> 4;
    const int l16  = lane & 15;

    // staging: thread t loads 16B chunks c=t and c=t+256; row=c>>2, k-off=(c&3)*8
    const _Float16* Ap = A + (size_t)(mb + (t >> 2)) * Ee + (t & 3) * 8;
    const _Float16* Bp = Bm + (size_t)h * Ee * Ee + (size_t)(nb + (t >> 2)) * Ee + (t & 3) * 8;

    f32x4 acc[4][4] = {};

    // prologue: stage k0=0 into buf 0
    async_ld16(&As[0][t * 8],        Ap);
    async_ld16(&As[0][2048 + t * 8], Ap + 64 * Ee);
    async_ld16(&Bs[0][t * 8],        Bp);
    async_ld16(&Bs[0][2048 + t * 8], Bp + 64 * Ee);

    int buf = 0;
    for (int k0 = 0; k0 < Ee; k0 += 32) {
        __syncthreads();   // drains loads for `buf`; also closes reads of buf^1
        if (k0 + 32 < Ee) {
            int nb2 = buf ^ 1;
            async_ld16(&As[nb2][t * 8],        Ap + k0 + 32);
            async_ld16(&As[nb2][2048 + t * 8], Ap + 64 * Ee + k0 + 32);
            async_ld16(&Bs[nb2][t * 8],        Bp + k0 + 32);
            async_ld16(&Bs[nb2][2048 + t * 8], Bp + 64 * Ee + k0 + 32);
        }
        f16x8 a8[4], b8[4];
#pragma unroll
        for (int mt = 0; mt < 4; ++mt)
            a8[mt] = *(const f16x8*)(&As[buf][(wm + mt * 16 + l16) * 32 + quad * 8]);
#pragma unroll
        for (int nt = 0; nt < 4; ++nt)
            b8[nt] = *(const f16x8*)(&Bs[buf][(wn + nt * 16 + l16) * 32 + quad * 8]);
#pragma unroll
        for (int mt = 0; mt < 4; ++mt)
#pragma unroll
            for (int nt = 0; nt < 4; ++nt)
                acc[mt][nt] = __builtin_amdgcn_mfma_f32_16x16x32_f16(a8[mt], b8[nt], acc[mt][nt], 0, 0, 0);
        buf ^= 1;
    }

    // BN partial sums: reduce over rows (mt,r) then across quads (lanes xor 16,32)
#pragma unroll
    for (int nt = 0; nt < 4; ++nt) {
        float s = 0.f, ss = 0.f;
#pragma unroll
        for (int mt = 0; mt < 4; ++mt)
#pragma unroll
            for (int r = 0; r < 4; ++r) { float v = acc[mt][nt][r]; s += v; ss += v * v; }
        s  += __shfl_xor(s, 16, 64);  s  += __shfl_xor(s, 32, 64);
        ss += __shfl_xor(ss, 16, 64); ss += __shfl_xor(ss, 32, 64);
        if (quad == 0) {
            int col = nb + wn + nt * 16 + l16;
            atomicAdd(&sums[h * Ee + col], s);
            atomicAdd(&sumsq[h * Ee + col], ss);
        }
    }

    // store C (f16): C/D layout col=lane&15, row=quad*4+reg
    _Float16* Cp = C + (size_t)h * Nn * Ee;
#pragma unroll
    for (int mt = 0; mt < 4; ++mt)
#pragma unroll
        for (int r = 0; r < 4; ++r) {
            int row = mb + wm + mt * 16 + quad * 4 + r;
            size_t off = (size_t)row * Ee + nb + wn + l16;
#pragma unroll
            for (int nt = 0; nt < 4; ++nt)
                Cp[off + nt * 16] = (_Float16)acc[mt][nt][r];
        }
}

// ---------------- K2: finalize BN stats into affine coefs -----------------------
__global__ __launch_bounds__(256) void stats_kernel(const float* __restrict__ sums,
                                                    const float* __restrict__ sumsq,
                                                    const float* __restrict__ bnw,
                                                    const float* __restrict__ bnb,
                                                    float* __restrict__ cA,
                                                    float* __restrict__ cB) {
    int i = blockIdx.x * 256 + threadIdx.x;    // 0..4095
    float mean = sums[i] * (1.0f / Nn);
    float var  = sumsq[i] * (1.0f / Nn) - mean * mean;
    float inv  = rsqrtf(var + BN_EPS_);
    float a    = bnw[i] * inv;
    cA[i] = a;
    cB[i] = bnb[i] - mean * a;
}

// ---------------- K3: per-row head scan: sparsemax (Michelot, DPP reductions) ---
// 256 threads = 4 waves, each wave owns one row n. Lane holds elems
// [lane*4, lane*4+4) and [256+lane*4, 256+lane*4+4)  (coalesced float4 chunks).
__global__ __launch_bounds__(256) void rows_kernel(const float* __restrict__ x,
                                                   const _Float16* __restrict__ lg,
                                                   const float* __restrict__ cA,
                                                   const float* __restrict__ cB,
                                                   float* __restrict__ out) {
    const int n    = blockIdx.x * 4 + (threadIdx.x >> 6);
    const int lane = threadIdx.x & 63;
    const int e0   = lane * 4;                 // first chunk; second at +256
    const int bb   = n >> 9;                   // n / Tt
    const int tt   = n & 511;                  // n % Tt

    float xr[8], prior[8], z[8], mk[8];
    {
        const float* xp = x + (size_t)n * Ee;
        float4 x0 = *(const float4*)(xp + e0);
        float4 x1 = *(const float4*)(xp + 256 + e0);
        xr[0]=x0.x; xr[1]=x0.y; xr[2]=x0.z; xr[3]=x0.w;
        xr[4]=x1.x; xr[5]=x1.y; xr[6]=x1.z; xr[7]=x1.w;
    }
#pragma unroll
    for (int j = 0; j < 8; ++j) prior[j] = 1.0f;

    float* omx = out;                               // (H,B,T,E) flat = (H,N,E)
    float* omk = out + (size_t)Hh * Nn * Ee;        // (B,H,T,E)

    // software-pipelined lg loads (addresses independent of the prior chain)
    const _Float16* lp0 = lg + (size_t)n * Ee;
    f16x4 l0 = *(const f16x4*)(lp0 + e0);
    f16x4 l1 = *(const f16x4*)(lp0 + 256 + e0);

#pragma unroll
    for (int h = 0; h < Hh; ++h) {
        f16x4 n0, n1;
        if (h + 1 < Hh) {
            const _Float16* lpn = lg + (size_t)(h + 1) * Nn * Ee + (size_t)n * Ee;
            n0 = *(const f16x4*)(lpn + e0);
            n1 = *(const f16x4*)(lpn + 256 + e0);
        }
        const float* ap = cA + h * Ee;
        const float* bp = cB + h * Ee;
        float4 a0 = *(const float4*)(ap + e0);
        float4 a1 = *(const float4*)(ap + 256 + e0);
        float4 b0 = *(const float4*)(bp + e0);
        float4 b1 = *(const float4*)(bp + 256 + e0);
        float av[8] = {a0.x,a0.y,a0.z,a0.w,a1.x,a1.y,a1.z,a1.w};
        float bv[8] = {b0.x,b0.y,b0.z,b0.w,b1.x,b1.y,b1.z,b1.w};
        float lv[8] = {(float)l0[0],(float)l0[1],(float)l0[2],(float)l0[3],
                       (float)l1[0],(float)l1[1],(float)l1[2],(float)l1[3]};
#pragma unroll
        for (int j = 0; j < 8; ++j)
            z[j] = (lv[j] * av[j] + bv[j]) * prior[j];

        // Michelot (exact sparsemax threshold), DPP wave reductions.
        float sl = 0.f;
#pragma unroll
        for (int j = 0; j < 8; ++j) sl += z[j];
        float tau = (dpp_sum64(sl) - 1.0f) * (1.0f / 512.0f);
        int cprev = 512;
        for (int it = 0; it < 64; ++it) {
            float s2 = 0.f, cf = 0.f;
#pragma unroll
            for (int j = 0; j < 8; ++j) {
                bool p = z[j] > tau;
                s2 += p ? z[j] : 0.0f;
                cf += p ? 1.0f : 0.0f;
            }
            float S = dpp_sum64(s2);
            float Cc = dpp_sum64(cf);
            int c = (int)Cc;
            if (c == cprev) break;
            cprev = c;
            tau = (S - 1.0f) / Cc;
        }

#pragma unroll
        for (int j = 0; j < 8; ++j) {
            mk[j] = fmaxf(z[j] - tau, 0.0f);
            prior[j] *= fmaxf(GAMMA_ - mk[j], 0.0f);
        }

        size_t oxoff = ((size_t)h * Nn + n) * Ee;
        size_t okoff = (((size_t)bb * Hh + h) * Tt + tt) * Ee;
        f32x4 vx0 = {xr[0]*mk[0], xr[1]*mk[1], xr[2]*mk[2], xr[3]*mk[3]};
        f32x4 vx1 = {xr[4]*mk[4], xr[5]*mk[5], xr[6]*mk[6], xr[7]*mk[7]};
        f32x4 vm0 = {mk[0], mk[1], mk[2], mk[3]};
        f32x4 vm1 = {mk[4], mk[5], mk[6], mk[7]};
        __builtin_nontemporal_store(vx0, (f32x4*)(omx + oxoff + e0));
        __builtin_nontemporal_store(vx1, (f32x4*)(omx + oxoff + 256 + e0));
        __builtin_nontemporal_store(vm0, (f32x4*)(omk + okoff + e0));
        __builtin_nontemporal_store(vm1, (f32x4*)(omk + okoff + 256 + e0));
        l0 = n0; l1 = n1;
    }
}

extern "C" void kernel_launch(void* const* d_in, const int* in_sizes, int n_in,
                              void* d_out, int out_size, void* d_ws, size_t ws_size,
                              hipStream_t stream) {
    const float* x   = (const float*)d_in[0];
    const float* W   = (const float*)d_in[1];
    const float* bnw = (const float*)d_in[2];
    const float* bnb = (const float*)d_in[3];
    float* out = (float*)d_out;

    uint8_t* ws = (uint8_t*)d_ws;
    _Float16* xh = (_Float16*)(ws);                    // 16,777,216 B
    _Float16* wh = (_Float16*)(ws + 16777216);         //  4,194,304 B
    _Float16* lg = (_Float16*)(ws + 20971520);         // 134,217,728 B
    float* sums  = (float*)(ws + 155189248);           // 16,384 B
    float* sumsq = (float*)(ws + 155205632);           // 16,384 B
    float* cA    = (float*)(ws + 155222016);           // 16,384 B
    float* cB    = (float*)(ws + 155238400);           // 16,384 B (total ~148 MB)

    hipMemsetAsync(sums, 0, 2 * 4096 * sizeof(float), stream);  // sums+sumsq contiguous

    cvt_kernel<<<10240, 256, 0, stream>>>(x, W, xh, wh);
    gemm_kernel<<<dim3(128, 4, 8), 256, 0, stream>>>(xh, wh, lg, sums, sumsq);
    stats_kernel<<<16, 256, 0, stream>>>(sums, sumsq, bnw, bnb, cA, cB);
    rows_kernel<<<4096, 256, 0, stream>>>(x, lg, cA, cB, out);
}